// Round 1
// baseline (955.851 us; speedup 1.0000x reference)
//
#include <hip/hip_runtime.h>
#include <math.h>

#define kB 128
#define kS 50
#define kD 64
#define kL 2
#define kItems 50000
#define kEps 1e-5f
#define PAD 65   // LDS row stride (floats) for transformer arrays: 65 mod 32 = 1 -> conflict-free column walks

__device__ __forceinline__ float wsum(float v) {
#pragma unroll
    for (int off = 32; off; off >>= 1) v += __shfl_xor(v, off, 64);
    return v;
}
__device__ __forceinline__ float wmax(float v) {
#pragma unroll
    for (int off = 32; off; off >>= 1) v = fmaxf(v, __shfl_xor(v, off, 64));
    return v;
}

// One block per batch element. Whole [S,D] activation set lives in LDS.
__global__ __launch_bounds__(256) void transformer_kernel(
    const int* __restrict__ item_ids, const float* __restrict__ emb,
    const float* __restrict__ pos_emb,
    const float* __restrict__ Wq, const float* __restrict__ Wk,
    const float* __restrict__ Wv,
    const float* __restrict__ W1, const float* __restrict__ b1,
    const float* __restrict__ W2, const float* __restrict__ b2,
    const float* __restrict__ ln_g, const float* __restrict__ ln_b,
    float* __restrict__ X)
{
    const int b    = blockIdx.x;
    const int tid  = threadIdx.x;
    const int lane = tid & 63;
    const int wave = tid >> 6;

    __shared__ float xs[kS][PAD];
    __shared__ float qs[kS][PAD];   // Q, later reused for FFN output
    __shared__ float ks[kS][PAD];
    __shared__ float vs[kS][PAD];
    __shared__ float as[kS][PAD];   // attention out, later reused for hidden h
    __shared__ float ps[4][64];     // per-wave softmax row

    // x = emb[item] + pos
    for (int i = tid; i < kS * kD; i += 256) {
        int s = i >> 6, d = i & 63;
        int item = item_ids[b * kS + s];
        xs[s][d] = emb[(size_t)item * kD + d] + pos_emb[s * kD + d];
    }
    __syncthreads();

    for (int l = 0; l < kL; ++l) {
        const float* wq = Wq + l * kD * kD;
        const float* wk = Wk + l * kD * kD;
        const float* wv = Wv + l * kD * kD;
        const float* g  = ln_g + l * kD;
        const float* be = ln_b + l * kD;

        // Q,K,V = x @ W.T   (y[s][e] = sum_d x[s][d] * W[e][d])
        for (int i = tid; i < 3 * kS * kD; i += 256) {
            int m = i / (kS * kD);
            int r = i % (kS * kD);
            int s = r >> 6, e = r & 63;
            const float* w = (m == 0 ? wq : m == 1 ? wk : wv) + e * kD;
            float acc = 0.f;
#pragma unroll
            for (int d = 0; d < kD; ++d) acc = fmaf(xs[s][d], w[d], acc);
            float* dst = (m == 0 ? &qs[0][0] : m == 1 ? &ks[0][0] : &vs[0][0]);
            dst[s * PAD + e] = acc;
        }
        __syncthreads();

        // causal attention: one wave per q-row (no barriers inside; trip counts differ)
        for (int q = wave; q < kS; q += 4) {
            int k = lane;
            float sc = -INFINITY;
            if (k <= q) {
                float acc = 0.f;
#pragma unroll
                for (int d = 0; d < kD; ++d) acc = fmaf(qs[q][d], ks[k][d], acc);
                sc = acc * 0.125f; // 1/sqrt(64)
            }
            float mx = wmax(sc);
            float ev = (k <= q) ? __expf(sc - mx) : 0.f;
            float sm = wsum(ev);
            ps[wave][lane] = ev / sm;            // same-wave write->read, waitcnt ordered
            float acc = 0.f;
            for (int kk = 0; kk <= q; ++kk)
                acc = fmaf(ps[wave][kk], vs[kk][lane], acc);
            as[q][lane] = acc;
        }
        __syncthreads();

        // x = LN(x + attn)
        for (int s = wave; s < kS; s += 4) {
            float v  = xs[s][lane] + as[s][lane];
            float mu = wsum(v) * (1.f / 64.f);
            float dv = v - mu;
            float var = wsum(dv * dv) * (1.f / 64.f);
            xs[s][lane] = fmaf(g[lane] * dv, rsqrtf(var + kEps), be[lane]);
        }
        __syncthreads();

        // h = relu(x @ W1.T + b1)
        for (int i = tid; i < kS * kD; i += 256) {
            int s = i >> 6, e = i & 63;
            const float* w = W1 + l * kD * kD + e * kD;
            float acc = b1[l * kD + e];
#pragma unroll
            for (int d = 0; d < kD; ++d) acc = fmaf(xs[s][d], w[d], acc);
            as[s][e] = fmaxf(acc, 0.f);
        }
        __syncthreads();

        // ff = h @ W2.T + b2  -> qs
        for (int i = tid; i < kS * kD; i += 256) {
            int s = i >> 6, e = i & 63;
            const float* w = W2 + l * kD * kD + e * kD;
            float acc = b2[l * kD + e];
#pragma unroll
            for (int d = 0; d < kD; ++d) acc = fmaf(as[s][d], w[d], acc);
            qs[s][e] = acc;
        }
        __syncthreads();

        // x = LN(x + ff)
        for (int s = wave; s < kS; s += 4) {
            float v  = xs[s][lane] + qs[s][lane];
            float mu = wsum(v) * (1.f / 64.f);
            float dv = v - mu;
            float var = wsum(dv * dv) * (1.f / 64.f);
            xs[s][lane] = fmaf(g[lane] * dv, rsqrtf(var + kEps), be[lane]);
        }
        __syncthreads();
    }

    for (int i = tid; i < kS * kD; i += 256) {
        int s = i >> 6, d = i & 63;
        X[(size_t)(b * kS + s) * kD + d] = xs[s][d];
    }
}

// logits[m][n] = sum_d X[m][d] * emb[n][d]   -- 64x64 tile per block, 4x4 per thread
__global__ __launch_bounds__(256) void logits_kernel(
    const float* __restrict__ X, const float* __restrict__ E,
    float* __restrict__ out)
{
    const int tid = threadIdx.x;
    const int tx  = tid & 15;
    const int ty  = tid >> 4;
    const int m0  = blockIdx.y * 64;
    const int n0  = blockIdx.x * 64;

    __shared__ float As[64][68];    // A rows (k contiguous), stride 68 keeps float4 alignment
    __shared__ float EsT[64][68];   // E transposed: EsT[k][n_local]

    // load A tile: 64 rows x 64 k, float4 per thread x4
    for (int i = tid; i < 64 * 16; i += 256) {
        int r  = i >> 4;
        int c4 = (i & 15) * 4;
        float4 v = *(const float4*)&X[(size_t)(m0 + r) * 64 + c4];
        *(float4*)&As[r][c4] = v;
    }
    // load E tile transposed (coalesced global read, scalar LDS writes)
    for (int i = tid; i < 64 * 16; i += 256) {
        int r  = i >> 4;          // local n
        int c4 = (i & 15) * 4;    // k start
        int n  = n0 + r;
        float4 v = (n < kItems) ? *(const float4*)&E[(size_t)n * 64 + c4]
                                : make_float4(0.f, 0.f, 0.f, 0.f);
        EsT[c4 + 0][r] = v.x;
        EsT[c4 + 1][r] = v.y;
        EsT[c4 + 2][r] = v.z;
        EsT[c4 + 3][r] = v.w;
    }
    __syncthreads();

    float acc[4][4] = {};
#pragma unroll
    for (int k4 = 0; k4 < 16; ++k4) {
        float a[4][4];
#pragma unroll
        for (int i = 0; i < 4; ++i) {
            float4 av = *(const float4*)&As[ty * 4 + i][k4 * 4];  // broadcast within phase: free
            a[i][0] = av.x; a[i][1] = av.y; a[i][2] = av.z; a[i][3] = av.w;
        }
#pragma unroll
        for (int kk = 0; kk < 4; ++kk) {
            float4 evv = *(const float4*)&EsT[k4 * 4 + kk][tx * 4]; // 16 lanes x 16B contiguous: conflict-free
            float e[4] = {evv.x, evv.y, evv.z, evv.w};
#pragma unroll
            for (int i = 0; i < 4; ++i)
#pragma unroll
                for (int j = 0; j < 4; ++j)
                    acc[i][j] = fmaf(a[i][kk], e[j], acc[i][j]);
        }
    }

#pragma unroll
    for (int i = 0; i < 4; ++i) {
        int m = m0 + ty * 4 + i;
        int n = n0 + tx * 4;
        if (n < kItems) {   // n,kItems both multiples of 4 -> whole float4 in-bounds
            float4 v = make_float4(acc[i][0], acc[i][1], acc[i][2], acc[i][3]);
            *(float4*)&out[(size_t)m * kItems + n] = v;
        }
    }
}

extern "C" void kernel_launch(void* const* d_in, const int* in_sizes, int n_in,
                              void* d_out, int out_size, void* d_ws, size_t ws_size,
                              hipStream_t stream) {
    const int*   item_ids = (const int*)d_in[0];
    const float* emb      = (const float*)d_in[1];
    const float* pos_emb  = (const float*)d_in[2];
    const float* Wq       = (const float*)d_in[3];
    const float* Wk       = (const float*)d_in[4];
    const float* Wv       = (const float*)d_in[5];
    const float* W1       = (const float*)d_in[6];
    const float* b1       = (const float*)d_in[7];
    const float* W2       = (const float*)d_in[8];
    const float* b2       = (const float*)d_in[9];
    const float* ln_g     = (const float*)d_in[10];
    const float* ln_b     = (const float*)d_in[11];

    float* X   = (float*)d_ws;          // [B*S, D] transformer output, 1.64 MB
    float* out = (float*)d_out;         // [B*S, kItems]

    transformer_kernel<<<kB, 256, 0, stream>>>(item_ids, emb, pos_emb,
                                               Wq, Wk, Wv, W1, b1, W2, b2,
                                               ln_g, ln_b, X);
    dim3 grid((kItems + 63) / 64, (kB * kS) / 64);
    logits_kernel<<<grid, 256, 0, stream>>>(X, emb, out);
}

// Round 2
// 605.954 us; speedup vs baseline: 1.5774x; 1.5774x over previous
//
#include <hip/hip_runtime.h>
#include <math.h>

#define kB 128
#define kS 50
#define kD 64
#define kL 2
#define kItems 50000
#define kEps 1e-5f
#define PAD 68   // floats; row byte stride 272 = 16*17 -> float4-aligned rows, row-wise access conflict-free

typedef __bf16 bf16x8 __attribute__((ext_vector_type(8)));
typedef float  f32x4v __attribute__((ext_vector_type(4)));

__device__ __forceinline__ float wsum(float v) {
#pragma unroll
    for (int off = 32; off; off >>= 1) v += __shfl_xor(v, off, 64);
    return v;
}
__device__ __forceinline__ float wmax(float v) {
#pragma unroll
    for (int off = 32; off; off >>= 1) v = fmaxf(v, __shfl_xor(v, off, 64));
    return v;
}
__device__ __forceinline__ unsigned short f2bf(float x) {  // RNE
    unsigned u = __builtin_bit_cast(unsigned, x);
    u += 0x7FFFu + ((u >> 16) & 1u);
    return (unsigned short)(u >> 16);
}
__device__ __forceinline__ float dot4(const float4 a, const float4 b) {
    return fmaf(a.x, b.x, fmaf(a.y, b.y, fmaf(a.z, b.z, a.w * b.w)));
}

// One block per batch element. Whole [S,D] activation set lives in LDS.
__global__ __launch_bounds__(256) void transformer_kernel(
    const int* __restrict__ item_ids, const float* __restrict__ emb,
    const float* __restrict__ pos_emb,
    const float* __restrict__ Wq, const float* __restrict__ Wk,
    const float* __restrict__ Wv,
    const float* __restrict__ W1, const float* __restrict__ b1,
    const float* __restrict__ W2, const float* __restrict__ b2,
    const float* __restrict__ ln_g, const float* __restrict__ ln_b,
    unsigned short* __restrict__ Xb)   // [B*S, D] bf16 output
{
    const int b    = blockIdx.x;
    const int tid  = threadIdx.x;
    const int lane = tid & 63;
    const int wave = tid >> 6;

    __shared__ float xs[kS][PAD];
    __shared__ float qs[kS][PAD];   // Q, later reused for FFN output
    __shared__ float ks[kS][PAD];
    __shared__ float vs[kS][PAD];
    __shared__ float as[kS][PAD];   // attention out, later reused for hidden h
    __shared__ float ps[4][64];     // per-wave softmax row

    for (int i = tid; i < kS * kD; i += 256) {
        int s = i >> 6, d = i & 63;
        int item = item_ids[b * kS + s];
        xs[s][d] = emb[(size_t)item * kD + d] + pos_emb[s * kD + d];
    }
    __syncthreads();

    for (int l = 0; l < kL; ++l) {
        const float* wq = Wq + l * kD * kD;
        const float* wk = Wk + l * kD * kD;
        const float* wv = Wv + l * kD * kD;
        const float* g  = ln_g + l * kD;
        const float* be = ln_b + l * kD;

        // Q,K,V = x @ W.T
        for (int i = tid; i < 3 * kS * kD; i += 256) {
            int m = i / (kS * kD);
            int r = i % (kS * kD);
            int s = r >> 6, e = r & 63;
            const float4* w  = (const float4*)((m == 0 ? wq : m == 1 ? wk : wv) + e * kD);
            const float4* xv = (const float4*)&xs[s][0];
            float acc = 0.f;
#pragma unroll
            for (int d4 = 0; d4 < 16; ++d4) acc += dot4(xv[d4], w[d4]);
            float* dst = (m == 0 ? &qs[0][0] : m == 1 ? &ks[0][0] : &vs[0][0]);
            dst[s * PAD + e] = acc;
        }
        __syncthreads();

        // causal attention: one wave per q-row
        for (int q = wave; q < kS; q += 4) {
            int k = lane;
            float sc = -INFINITY;
            if (k <= q) {
                const float4* qv = (const float4*)&qs[q][0];
                const float4* kv = (const float4*)&ks[k][0];
                float acc = 0.f;
#pragma unroll
                for (int d4 = 0; d4 < 16; ++d4) acc += dot4(qv[d4], kv[d4]);
                sc = acc * 0.125f;
            }
            float mx = wmax(sc);
            float ev = (k <= q) ? __expf(sc - mx) : 0.f;
            float sm = wsum(ev);
            ps[wave][lane] = ev / sm;
            float acc = 0.f;
            for (int kk = 0; kk <= q; ++kk)
                acc = fmaf(ps[wave][kk], vs[kk][lane], acc);
            as[q][lane] = acc;
        }
        __syncthreads();

        // x = LN(x + attn)
        for (int s = wave; s < kS; s += 4) {
            float v  = xs[s][lane] + as[s][lane];
            float mu = wsum(v) * (1.f / 64.f);
            float dv = v - mu;
            float var = wsum(dv * dv) * (1.f / 64.f);
            xs[s][lane] = fmaf(g[lane] * dv, rsqrtf(var + kEps), be[lane]);
        }
        __syncthreads();

        // h = relu(x @ W1.T + b1)
        for (int i = tid; i < kS * kD; i += 256) {
            int s = i >> 6, e = i & 63;
            const float4* w  = (const float4*)(W1 + l * kD * kD + e * kD);
            const float4* xv = (const float4*)&xs[s][0];
            float acc = b1[l * kD + e];
#pragma unroll
            for (int d4 = 0; d4 < 16; ++d4) acc += dot4(xv[d4], w[d4]);
            as[s][e] = fmaxf(acc, 0.f);
        }
        __syncthreads();

        // ff = h @ W2.T + b2  -> qs
        for (int i = tid; i < kS * kD; i += 256) {
            int s = i >> 6, e = i & 63;
            const float4* w  = (const float4*)(W2 + l * kD * kD + e * kD);
            const float4* hv = (const float4*)&as[s][0];
            float acc = b2[l * kD + e];
#pragma unroll
            for (int d4 = 0; d4 < 16; ++d4) acc += dot4(hv[d4], w[d4]);
            qs[s][e] = acc;
        }
        __syncthreads();

        // x = LN(x + ff)
        for (int s = wave; s < kS; s += 4) {
            float v  = xs[s][lane] + qs[s][lane];
            float mu = wsum(v) * (1.f / 64.f);
            float dv = v - mu;
            float var = wsum(dv * dv) * (1.f / 64.f);
            xs[s][lane] = fmaf(g[lane] * dv, rsqrtf(var + kEps), be[lane]);
        }
        __syncthreads();
    }

    for (int i = tid; i < kS * kD; i += 256) {
        int s = i >> 6, d = i & 63;
        Xb[(size_t)(b * kS + s) * kD + d] = f2bf(xs[s][d]);
    }
}

// logits[m][n] = sum_d X[m][d] * E[n][d]
// One block per 64-wide n-strip; block loops over all 100 m-tiles.
// E staged once (f32->bf16, XOR-swizzled LDS); B-fragments hoisted out of the m-loop.
__global__ __launch_bounds__(256) void logits_kernel(
    const unsigned short* __restrict__ Xb, const float* __restrict__ E,
    float* __restrict__ out)
{
    const int tid  = threadIdx.x;
    const int lane = tid & 63;
    const int wave = tid >> 6;
    const int n0   = blockIdx.x * 64;

    __shared__ __align__(16) unsigned short Es[64 * 64];  // swizzled [n][k] bf16
    __shared__ __align__(16) unsigned short Xs[64 * 64];  // swizzled [m][k] bf16

    // stage E strip, converting f32 -> bf16
    for (int i = tid; i < 64 * 16; i += 256) {
        int r  = i >> 4;           // local n
        int c4 = (i & 15) * 4;     // k
        int n  = n0 + r;
        float4 v = (n < kItems) ? *(const float4*)&E[(size_t)n * kD + c4]
                                : make_float4(0.f, 0.f, 0.f, 0.f);
        ushort4 u;
        u.x = f2bf(v.x); u.y = f2bf(v.y); u.z = f2bf(v.z); u.w = f2bf(v.w);
        int byte = (r * 128 + c4 * 2) ^ ((r & 7) << 4);
        *(ushort4*)((char*)Es + byte) = u;
    }
    __syncthreads();

    const int frow = lane & 15;    // fragment row/col index
    const int kq   = lane >> 4;    // k-quarter 0..3

    // hoist B-fragments (E is m-loop invariant): 4 n-chunks x 2 k-steps
    bf16x8 bfrag[4][2];
#pragma unroll
    for (int nc = 0; nc < 4; ++nc) {
        int brow = nc * 16 + frow;
        int base = brow * 128 + kq * 16;
        int swz  = (brow & 7) << 4;
        bfrag[nc][0] = *(const bf16x8*)((const char*)Es + ((base) ^ swz));
        bfrag[nc][1] = *(const bf16x8*)((const char*)Es + ((base + 64) ^ swz));
    }

    const int arow = wave * 16 + frow;
    const int abase = arow * 128 + kq * 16;
    const int aswz  = (arow & 7) << 4;

    for (int mt = 0; mt < 100; ++mt) {
        const int m0 = mt * 64;
        __syncthreads();   // previous iter's a-frag reads done before overwrite
        for (int i = tid; i < 512; i += 256) {
            int r = i >> 3, s = i & 7;
            float4 v = *(const float4*)&Xb[((size_t)(m0 + r)) * kD + s * 8];  // 8 bf16
            int byte = (r * 128 + s * 16) ^ ((r & 7) << 4);
            *(float4*)((char*)Xs + byte) = v;
        }
        __syncthreads();

        bf16x8 a0 = *(const bf16x8*)((const char*)Xs + ((abase) ^ aswz));
        bf16x8 a1 = *(const bf16x8*)((const char*)Xs + ((abase + 64) ^ aswz));

        f32x4v acc[4];
#pragma unroll
        for (int nc = 0; nc < 4; ++nc) {
            acc[nc] = (f32x4v){0.f, 0.f, 0.f, 0.f};
            acc[nc] = __builtin_amdgcn_mfma_f32_16x16x32_bf16(a0, bfrag[nc][0], acc[nc], 0, 0, 0);
            acc[nc] = __builtin_amdgcn_mfma_f32_16x16x32_bf16(a1, bfrag[nc][1], acc[nc], 0, 0, 0);
        }

        // C layout: col = lane&15, row = (lane>>4)*4 + reg
        const int mrow = m0 + wave * 16 + kq * 4;
#pragma unroll
        for (int nc = 0; nc < 4; ++nc) {
            int col = n0 + nc * 16 + frow;
            if (col < kItems) {
#pragma unroll
                for (int r = 0; r < 4; ++r)
                    out[(size_t)(mrow + r) * kItems + col] = acc[nc][r];
            }
        }
    }
}

extern "C" void kernel_launch(void* const* d_in, const int* in_sizes, int n_in,
                              void* d_out, int out_size, void* d_ws, size_t ws_size,
                              hipStream_t stream) {
    const int*   item_ids = (const int*)d_in[0];
    const float* emb      = (const float*)d_in[1];
    const float* pos_emb  = (const float*)d_in[2];
    const float* Wq       = (const float*)d_in[3];
    const float* Wk       = (const float*)d_in[4];
    const float* Wv       = (const float*)d_in[5];
    const float* W1       = (const float*)d_in[6];
    const float* b1       = (const float*)d_in[7];
    const float* W2       = (const float*)d_in[8];
    const float* b2       = (const float*)d_in[9];
    const float* ln_g     = (const float*)d_in[10];
    const float* ln_b     = (const float*)d_in[11];

    unsigned short* Xb = (unsigned short*)d_ws;   // [B*S, D] bf16, 0.8 MB
    float* out = (float*)d_out;

    transformer_kernel<<<kB, 256, 0, stream>>>(item_ids, emb, pos_emb,
                                               Wq, Wk, Wv, W1, b1, W2, b2,
                                               ln_g, ln_b, Xb);
    const int nblocks = (kItems + 63) / 64;   // 782
    logits_kernel<<<nblocks, 256, 0, stream>>>(Xb, emb, out);
}